// Round 8
// baseline (181.972 us; speedup 1.0000x reference)
//
#include <hip/hip_runtime.h>
#include <cstdint>

typedef __attribute__((ext_vector_type(8))) __bf16 bf16x8;
typedef __attribute__((ext_vector_type(4))) float f32x4;
using u16 = unsigned short;
using u32 = unsigned int;

#define D_MODEL 1024
#define N_HEADS 16
#define D_K     64
#define SEQ     2048
#define BATCH   2
#define NTOKENS (BATCH * SEQ)
#define SCALE   0.125f
#define LOG2E   1.44269504088896340736f
#define C2      (SCALE * LOG2E)

__device__ __forceinline__ u16 f32_to_bf16(float f) {
    union { float f; u32 u; } v; v.f = f;
    u32 r = (v.u + 0x7fffu + ((v.u >> 16) & 1u)) >> 16;
    return (u16)r;
}

// pack two f32 -> two bf16 (RNE) in ONE VALU op
__device__ __forceinline__ u32 cvt_pk_bf16(float a, float b) {
    u32 r;
    asm("v_cvt_pk_bf16_f32 %0, %1, %2" : "=v"(r) : "v"(a), "v"(b));
    return r;
}

// async global->LDS DMA, 16B/lane; LDS dst wave-uniform base + lane*16
typedef const __attribute__((address_space(1))) u32* gas_ptr;
typedef __attribute__((address_space(3))) u32* las_ptr;
__device__ __forceinline__ void gl2lds16(const u16* g, u16* l) {
    __builtin_amdgcn_global_load_lds((gas_ptr)g, (las_ptr)l, 16, 0, 0);
}

// ================= swizzle scheme (16B-granular, 3-bit: chunk ^= row&7) ============
// - LDS reads: within each 16-lane quarter-wave, chunk = (base+quad)^(l4&7) spans all 8
//   chunk slots -> 2 lanes/bank uniform = conflict-free (measured 0 in rounds 4/6).
// - Stores: the XOR maps the chunk PAIR {2c, 2c+1} to the SET {m, m+1} (contiguous 32B,
//   halves possibly swapped) -> 32B store runs preserved.  (Round-6's regression was the
//   V kappa COLUMN scatter, not this XOR; kappa now lives in K's row order.)

// ---------------- fp32 -> bf16 convert + chunk swizzle: x + 4 weights in ONE kernel ----------
__global__ __launch_bounds__(256) void cvt_all(const float* __restrict__ x,
                                               const float* __restrict__ Wq, const float* __restrict__ Wk,
                                               const float* __restrict__ Wv, const float* __restrict__ Wo,
                                               u16* __restrict__ xb,
                                               u16* __restrict__ wq, u16* __restrict__ wk,
                                               u16* __restrict__ wv, u16* __restrict__ wo) {
    const int NX = NTOKENS * D_MODEL;          // 4 M
    size_t i = (size_t)(blockIdx.x * 256 + threadIdx.x) * 4;
    const float* src; u16* dst; size_t off;
    if (i < (size_t)NX) { src = x; dst = xb; off = i; }
    else {
        size_t j = i - NX;
        int w = (int)(j >> 20);
        off = j & ((1u << 20) - 1);
        src = (w == 0) ? Wq : (w == 1) ? Wk : (w == 2) ? Wv : Wo;
        dst = (w == 0) ? wq : (w == 1) ? wk : (w == 2) ? wv : wo;
    }
    float4 f = *(const float4*)(src + off);
    u32 lo = (u32)f32_to_bf16(f.x) | ((u32)f32_to_bf16(f.y) << 16);
    u32 hi = (u32)f32_to_bf16(f.z) | ((u32)f32_to_bf16(f.w) << 16);
    uint2 o; o.x = lo; o.y = hi;
    // row = off>>10 ; chunk ^= row&7 within the 64-col slice
    size_t osw = (off & ~(size_t)63) | ((((off >> 3) & 7) ^ ((off >> 10) & 7)) << 3) | (off & 7);
    *(uint2*)(dst + osw) = o;
}

// ---------------- common 128x128 GEMM core: BK=64, minimum 2-phase pipeline ----------
// Sources pre-swizzled chunk^=row&7; staging linear gl2lds; ds_read_b128 at
// chunk (kk*4+quad)^(l4&7) -> conflict-free (measured 0, round 6).
__device__ __forceinline__ void gemm_core_128(const u16* __restrict__ Ab,
                                              const u16* __restrict__ Bb,
                                              u16* __restrict__ sm,
                                              f32x4 acc[4][4]) {
    const int tid  = threadIdx.x;
    const int wave = tid >> 6, lane = tid & 63;
    const int quad = lane >> 4, l4 = lane & 15, s7 = l4 & 7;
    const int wm = wave >> 1, wn = wave & 1;

    const int srow = tid >> 3, sch = tid & 7;          // staging: row 0..31 (+c*32), chunk 0..7
    const u16* Asrc = Ab + (size_t)srow * D_MODEL + sch * 8;
    const u16* Bsrc = Bb + (size_t)srow * D_MODEL + sch * 8;

    // buffer: base 0 or 16384 u16; A at base, B at base+8192
#define STG8(base_, kt_) do {                                                         \
    const size_t ko_ = (size_t)(kt_) * 64;                                            \
    u16* const Ad_ = sm + (base_) + wave * 512;                                       \
    u16* const Bd_ = sm + (base_) + 8192 + wave * 512;                                \
    _Pragma("unroll")                                                                 \
    for (int c_ = 0; c_ < 4; c_++)                                                    \
        gl2lds16(Asrc + (size_t)c_ * 32 * D_MODEL + ko_, Ad_ + c_ * 2048);            \
    _Pragma("unroll")                                                                 \
    for (int c_ = 0; c_ < 4; c_++)                                                    \
        gl2lds16(Bsrc + (size_t)c_ * 32 * D_MODEL + ko_, Bd_ + c_ * 2048);            \
} while (0)

    STG8(0, 0);
    asm volatile("s_waitcnt vmcnt(0)" ::: "memory");
    __builtin_amdgcn_s_barrier();

    for (int kt = 0; kt < 16; ++kt) {
        const int cur = (kt & 1) << 14;                  // 0 / 16384
        if (kt < 15) {                                   // issue next tile into other buffer
            if (kt & 1) STG8(0, kt + 1); else STG8(16384, kt + 1);
        }
        const u16* Ar = sm + cur;
        const u16* Br = sm + cur + 8192;
        bf16x8 af[4][2], bfr[4][2];
#pragma unroll
        for (int mt = 0; mt < 4; mt++) {
            const int row = wm * 64 + mt * 16 + l4;
#pragma unroll
            for (int kk = 0; kk < 2; kk++)
                af[mt][kk] = *(const bf16x8*)&Ar[row * 64 + (((kk << 2) + quad) ^ s7) * 8];
        }
#pragma unroll
        for (int nt = 0; nt < 4; nt++) {
            const int row = wn * 64 + nt * 16 + l4;
#pragma unroll
            for (int kk = 0; kk < 2; kk++)
                bfr[nt][kk] = *(const bf16x8*)&Br[row * 64 + (((kk << 2) + quad) ^ s7) * 8];
        }
        __builtin_amdgcn_s_setprio(1);
#pragma unroll
        for (int kk = 0; kk < 2; kk++)
#pragma unroll
            for (int mt = 0; mt < 4; mt++)
#pragma unroll
                for (int nt = 0; nt < 4; nt++)
                    acc[mt][nt] = __builtin_amdgcn_mfma_f32_16x16x32_bf16(af[mt][kk], bfr[nt][kk], acc[mt][nt], 0, 0, 0);
        __builtin_amdgcn_s_setprio(0);
        asm volatile("s_waitcnt vmcnt(0)" ::: "memory"); // next tile fully landed (mine)
        __builtin_amdgcn_s_barrier();                    // ... and everyone's; reads done too
    }
#undef STG8
}

// ---------------- Fused QKV projection GEMM ----------------
// Flat grid 768. bid<256: Q tiles; 256..511: K tiles; 512..767: V^T tiles (C = Wv x^T).
// Kb: kappa folded into ROW order (prow) + chunk^=prow&7.  Vt: natural + chunk^=feat&7.
// Both stores keep 32B-run address sets (see swizzle scheme note).
__global__ __launch_bounds__(256, 2) void gemm_qkv(const u16* __restrict__ xb,
                                                   const u16* __restrict__ wq,
                                                   const u16* __restrict__ wk,
                                                   const u16* __restrict__ wv,
                                                   u16* __restrict__ Qb, u16* __restrict__ Kb,
                                                   u16* __restrict__ Vt) {
    __shared__ __align__(16) u16 sm[32768];              // 64 KB: 2 x (A 16KB + B 16KB)
    const int bid = blockIdx.x;
    const u16 *Ab, *Bb;
    int m0, n0, sel;
    if (bid < 512) {
        sel = bid >> 8;                                  // 0=Q, 1=K
        const int t = bid & 255;
        m0 = (t >> 3) * 128; n0 = (t & 7) * 128;
        Ab = xb + (size_t)m0 * D_MODEL;
        Bb = (sel ? wk : wq) + (size_t)n0 * D_MODEL;
    } else {
        sel = 2;
        const int t = bid - 512;
        m0 = (t >> 5) * 128; n0 = (t & 31) * 128;        // m = features, n = tokens
        Ab = wv + (size_t)m0 * D_MODEL;
        Bb = xb + (size_t)n0 * D_MODEL;
    }

    f32x4 acc[4][4] = {};
    gemm_core_128(Ab, Bb, sm, acc);

    const int lane = threadIdx.x & 63, quad = lane >> 4, l4 = lane & 15;
    const int wave = threadIdx.x >> 6, wm = wave >> 1, wn = wave & 1;
#pragma unroll
    for (int mt = 0; mt < 4; mt++)
#pragma unroll
        for (int nt = 0; nt < 4; nt++)
#pragma unroll
            for (int r = 0; r < 4; r++) {
                const int mrow = wm * 64 + mt * 16 + quad * 4 + r;
                const int ncol = wn * 64 + nt * 16 + l4;
                const float v = acc[mt][nt][r];
                if (sel == 0) {
                    Qb[(size_t)(m0 + mrow) * D_MODEL + n0 + ncol] = f32_to_bf16(v * C2);
                } else if (sel == 1) {
                    // kappa row-permutation within 32-token group + chunk^=prow&7
                    const int k5 = mrow & 31;
                    const int prow = (mrow & 96) | (((k5 >> 2) & 1) << 4) |
                                     (((k5 >> 3) & 3) << 2) | (k5 & 3);
                    const int csw = (wn * 64) | (((nt * 2 + (l4 >> 3)) ^ (prow & 7)) << 3) | (l4 & 7);
                    Kb[(size_t)(m0 + prow) * D_MODEL + n0 + csw] = f32_to_bf16(v);
                } else {
                    // natural token order, chunk^=feature&7
                    const int csw = (wn * 64) | (((nt * 2 + (l4 >> 3)) ^ (mrow & 7)) << 3) | (l4 & 7);
                    Vt[(size_t)(m0 + mrow) * NTOKENS + n0 + csw] = f32_to_bf16(v);
                }
            }
}

// ---------------- Output projection GEMM: fp32 out ----------------
// A = attn output O (pre-swizzled store in attn), B = wo (pre-swizzled by cvt_all).
__global__ __launch_bounds__(256, 2) void gemm_out(const u16* __restrict__ A,
                                                   const u16* __restrict__ Bw,
                                                   float* __restrict__ C) {
    __shared__ __align__(16) u16 sm[32768];
    const int bid = blockIdx.x;
    const int m0 = (bid >> 3) * 128, n0 = (bid & 7) * 128;

    f32x4 acc[4][4] = {};
    gemm_core_128(A + (size_t)m0 * D_MODEL, Bw + (size_t)n0 * D_MODEL, sm, acc);

    const int lane = threadIdx.x & 63, quad = lane >> 4, l4 = lane & 15;
    const int wave = threadIdx.x >> 6, wm = wave >> 1, wn = wave & 1;
#pragma unroll
    for (int mt = 0; mt < 4; mt++)
#pragma unroll
        for (int nt = 0; nt < 4; nt++)
#pragma unroll
            for (int r = 0; r < 4; r++) {
                const int mrow = wm * 64 + mt * 16 + quad * 4 + r;
                const int ncol = wn * 64 + nt * 16 + l4;
                C[(size_t)(m0 + mrow) * D_MODEL + n0 + ncol] = acc[mt][nt][r];
            }
}

// ---------------- Flash attention v5c: gl2lds staging, no kv-split, 2-phase pipeline ----------
// Structure identical to round-7 (verified); only the swizzle constant reverted to
// sw7 = l4&7 (16B, 3-bit) and the O-store XOR to qrow&7.  kappa lives in Kb's row order.
__global__ __launch_bounds__(256, 4) void attn(const u16* __restrict__ Q,
                                               const u16* __restrict__ K,
                                               const u16* __restrict__ Vt,
                                               u16* __restrict__ O) {
    __shared__ __align__(16) u16 smem[16384];          // 32 KB: K 2x4096 + V 2x4096 u16
    u16* KsB = smem;
    u16* VsB = smem + 8192;

    const int tid  = threadIdx.x;
    const int wave = tid >> 6, lane = tid & 63;
    const int quad = lane >> 4, l4 = lane & 15;
    const int qg = wave;
    const int bid = blockIdx.x;
    const int h  = (bid & 7) | (((bid >> 3) & 1) << 3);
    const int b  = (bid >> 4) & 1;
    const int q0 = (bid >> 5) * 128;
    const size_t headoff = (size_t)b * SEQ * D_MODEL + (size_t)h * D_K;

    // staging sources (per-lane): wave w stages K token-rows [w*16,w*16+16) and
    // V feature-rows [w*16,w*16+16), 16B per lane, two calls of 8 rows each.
    const int srow8 = lane >> 3, sch = lane & 7;
    const u16* srcK = K  + headoff + (size_t)(wave * 16 + srow8) * D_MODEL + sch * 8;
    const u16* srcV = Vt + (size_t)(h * 64 + wave * 16 + srow8) * NTOKENS + (size_t)b * SEQ + sch * 8;
    u16* const dK0 = KsB + (wave * 16) * 64;
    u16* const dK1 = KsB + (wave * 16 + 8) * 64;
    u16* const dV0 = VsB + (wave * 16) * 64;
    u16* const dV1 = VsB + (wave * 16 + 8) * 64;

#define ASTG(buf_, t_) do {                                                  \
    const size_t kt_ = (size_t)(t_) * 64 * D_MODEL;                          \
    const size_t vt_ = (size_t)(t_) * 64;                                    \
    gl2lds16(srcK + kt_,                       dK0 + (buf_));                \
    gl2lds16(srcK + kt_ + 8 * D_MODEL,         dK1 + (buf_));                \
    gl2lds16(srcV + vt_,                       dV0 + (buf_));                \
    gl2lds16(srcV + vt_ + (size_t)8 * NTOKENS, dV1 + (buf_));                \
} while (0)

    // Q fragments straight from global (one-time): 2 q-subtiles x 2 k-halves
    bf16x8 qa[2][2];
#pragma unroll
    for (int qs = 0; qs < 2; qs++) {
        const u16* qp = Q + headoff + (size_t)(q0 + qg * 32 + qs * 16 + l4) * D_MODEL + quad * 8;
        qa[qs][0] = *(const bf16x8*)qp;
        qa[qs][1] = *(const bf16x8*)(qp + 32);
    }

    // all-ones bf16 B-fragment for denominator MFMA
    union { u32 u[4]; bf16x8 v; } onesu;
#pragma unroll
    for (int i = 0; i < 4; i++) onesu.u[i] = 0x3F803F80u;

    f32x4 acc_o[2][4] = {};
    f32x4 acc_l[2] = {};
    const int sw7 = l4 & 7;

    ASTG(0, 0);
    asm volatile("s_waitcnt vmcnt(0)" ::: "memory");
    __builtin_amdgcn_s_barrier();

    for (int it = 0; it < 32; ++it) {
        const int cur = (it & 1) ? 4096 : 0;
        if (it < 31) { if (it & 1) ASTG(0, it + 1); else ASTG(4096, it + 1); }
        const u16* ksr = KsB + cur;
        const u16* vsr = VsB + cur;

        // S^T = K Q^T for 64 keys (2 kf halves x 2 n2p tiles) x 32 q; exp2 -> pp per kf
        union { u32 u[4]; bf16x8 v; } pp[2][2];
#pragma unroll
        for (int kf = 0; kf < 2; kf++) {
            bf16x8 kb[2][2];
#pragma unroll
            for (int n2p = 0; n2p < 2; n2p++) {
                const int krow = kf * 32 + n2p * 16 + l4;
                kb[n2p][0] = *(const bf16x8*)&ksr[krow * 64 + ((quad       ^ sw7) * 8)];
                kb[n2p][1] = *(const bf16x8*)&ksr[krow * 64 + (((4 + quad) ^ sw7) * 8)];
            }
            f32x4 sacc[2][2] = {};
            __builtin_amdgcn_s_setprio(1);
#pragma unroll
            for (int qs = 0; qs < 2; qs++)
#pragma unroll
                for (int n2p = 0; n2p < 2; n2p++) {
                    sacc[qs][n2p] = __builtin_amdgcn_mfma_f32_16x16x32_bf16(kb[n2p][0], qa[qs][0], sacc[qs][n2p], 0, 0, 0);
                    sacc[qs][n2p] = __builtin_amdgcn_mfma_f32_16x16x32_bf16(kb[n2p][1], qa[qs][1], sacc[qs][n2p], 0, 0, 0);
                }
            __builtin_amdgcn_s_setprio(0);
#pragma unroll
            for (int qs = 0; qs < 2; qs++)
#pragma unroll
                for (int n2p = 0; n2p < 2; n2p++) {
                    float p0 = __builtin_amdgcn_exp2f(sacc[qs][n2p][0]);
                    float p1 = __builtin_amdgcn_exp2f(sacc[qs][n2p][1]);
                    float p2 = __builtin_amdgcn_exp2f(sacc[qs][n2p][2]);
                    float p3 = __builtin_amdgcn_exp2f(sacc[qs][n2p][3]);
                    pp[qs][kf].u[n2p * 2]     = cvt_pk_bf16(p0, p1);
                    pp[qs][kf].u[n2p * 2 + 1] = cvt_pk_bf16(p2, p3);
                }
        }

        // O += P V over both key-halves; denominator via constant-ones B fragment
        __builtin_amdgcn_s_setprio(1);
#pragma unroll
        for (int dvt = 0; dvt < 4; dvt++) {
            const int vrow = dvt * 16 + l4;
#pragma unroll
            for (int kf = 0; kf < 2; kf++) {
                bf16x8 vfr = *(const bf16x8*)&vsr[vrow * 64 + ((((kf << 2) + quad) ^ sw7) * 8)];
#pragma unroll
                for (int qs = 0; qs < 2; qs++)
                    acc_o[qs][dvt] = __builtin_amdgcn_mfma_f32_16x16x32_bf16(pp[qs][kf].v, vfr, acc_o[qs][dvt], 0, 0, 0);
            }
        }
#pragma unroll
        for (int qs = 0; qs < 2; qs++)
#pragma unroll
            for (int kf = 0; kf < 2; kf++)
                acc_l[qs] = __builtin_amdgcn_mfma_f32_16x16x32_bf16(pp[qs][kf].v, onesu.v, acc_l[qs], 0, 0, 0);
        __builtin_amdgcn_s_setprio(0);

        asm volatile("s_waitcnt vmcnt(0)" ::: "memory");
        __builtin_amdgcn_s_barrier();
    }

    // epilogue: acc_l is the FULL row sum (each wave saw all keys) -> direct store
#pragma unroll
    for (int qs = 0; qs < 2; qs++)
#pragma unroll
        for (int r = 0; r < 4; r++) {
            const float linv = 1.f / acc_l[qs][r];
            const int qrow = q0 + qg * 32 + qs * 16 + quad * 4 + r;
#pragma unroll
            for (int dvt = 0; dvt < 4; dvt++) {
                // GEMM chunk swizzle: chunk ^= qrow&7 within the head's 64-col slice
                const int csw = (((dvt * 2 + (l4 >> 3)) ^ (qrow & 7)) << 3) | (l4 & 7);
                O[headoff + (size_t)qrow * D_MODEL + csw] = f32_to_bf16(acc_o[qs][dvt][r] * linv);
            }
        }
#undef ASTG
}

// ---------------- launch ----------------
extern "C" void kernel_launch(void* const* d_in, const int* in_sizes, int n_in,
                              void* d_out, int out_size, void* d_ws, size_t ws_size,
                              hipStream_t stream) {
    const float* x  = (const float*)d_in[0];
    const float* Wq = (const float*)d_in[1];
    const float* Wk = (const float*)d_in[2];
    const float* Wv = (const float*)d_in[3];
    const float* Wo = (const float*)d_in[4];

    const int NW = D_MODEL * D_MODEL;      // 1,048,576

    char* ws = (char*)d_ws;
    u16* xb = (u16*)ws;                    // 8 MB; reused as attn output O
    u16* wq = (u16*)(ws + (8u << 20));
    u16* wk = wq + NW;
    u16* wv = wk + NW;
    u16* wo = wv + NW;
    u16* Qb  = (u16*)(ws + (16u << 20));
    u16* Kb  = (u16*)(ws + (24u << 20));   // kappa-row-permuted + chunk-swizzled
    u16* Vtb = (u16*)(ws + (32u << 20));   // V^T natural order + chunk-swizzled

    cvt_all<<<8192, 256, 0, stream>>>(x, Wq, Wk, Wv, Wo, xb, wq, wk, wv, wo);

    gemm_qkv<<<768, 256, 0, stream>>>(xb, wq, wk, wv, Qb, Kb, Vtb);

    attn<<<512, 256, 0, stream>>>(Qb, Kb, Vtb, xb);

    gemm_out<<<256, 256, 0, stream>>>(xb, wo, (float*)d_out);
}

// Round 9
// 168.481 us; speedup vs baseline: 1.0801x; 1.0801x over previous
//
#include <hip/hip_runtime.h>
#include <cstdint>

typedef __attribute__((ext_vector_type(8))) __bf16 bf16x8;
typedef __attribute__((ext_vector_type(4))) float f32x4;
using u16 = unsigned short;
using u32 = unsigned int;

#define D_MODEL 1024
#define N_HEADS 16
#define D_K     64
#define SEQ     2048
#define BATCH   2
#define NTOKENS (BATCH * SEQ)
#define SCALE   0.125f
#define LOG2E   1.44269504088896340736f
#define C2      (SCALE * LOG2E)

__device__ __forceinline__ u16 f32_to_bf16(float f) {
    union { float f; u32 u; } v; v.f = f;
    u32 r = (v.u + 0x7fffu + ((v.u >> 16) & 1u)) >> 16;
    return (u16)r;
}

// pack two f32 -> two bf16 (RNE) in ONE VALU op
__device__ __forceinline__ u32 cvt_pk_bf16(float a, float b) {
    u32 r;
    asm("v_cvt_pk_bf16_f32 %0, %1, %2" : "=v"(r) : "v"(a), "v"(b));
    return r;
}

// async global->LDS DMA, 16B/lane; LDS dst wave-uniform base + lane*16
typedef const __attribute__((address_space(1))) u32* gas_ptr;
typedef __attribute__((address_space(3))) u32* las_ptr;
__device__ __forceinline__ void gl2lds16(const u16* g, u16* l) {
    __builtin_amdgcn_global_load_lds((gas_ptr)g, (las_ptr)l, 16, 0, 0);
}

// ================= swizzle scheme (16B-granular, 3-bit: chunk ^= row&7) ============
// Verified: gemm SQ_LDS_BANK_CONFLICT = 0 (rounds 4/6/8); stores keep 32B runs.

// ---------------- fp32 -> bf16 convert + chunk swizzle: x + 4 weights in ONE kernel ----------
__global__ __launch_bounds__(256) void cvt_all(const float* __restrict__ x,
                                               const float* __restrict__ Wq, const float* __restrict__ Wk,
                                               const float* __restrict__ Wv, const float* __restrict__ Wo,
                                               u16* __restrict__ xb,
                                               u16* __restrict__ wq, u16* __restrict__ wk,
                                               u16* __restrict__ wv, u16* __restrict__ wo) {
    const int NX = NTOKENS * D_MODEL;          // 4 M
    size_t i = (size_t)(blockIdx.x * 256 + threadIdx.x) * 4;
    const float* src; u16* dst; size_t off;
    if (i < (size_t)NX) { src = x; dst = xb; off = i; }
    else {
        size_t j = i - NX;
        int w = (int)(j >> 20);
        off = j & ((1u << 20) - 1);
        src = (w == 0) ? Wq : (w == 1) ? Wk : (w == 2) ? Wv : Wo;
        dst = (w == 0) ? wq : (w == 1) ? wk : (w == 2) ? wv : wo;
    }
    float4 f = *(const float4*)(src + off);
    u32 lo = (u32)f32_to_bf16(f.x) | ((u32)f32_to_bf16(f.y) << 16);
    u32 hi = (u32)f32_to_bf16(f.z) | ((u32)f32_to_bf16(f.w) << 16);
    uint2 o; o.x = lo; o.y = hi;
    // row = off>>10 ; chunk ^= row&7 within the 64-col slice
    size_t osw = (off & ~(size_t)63) | ((((off >> 3) & 7) ^ ((off >> 10) & 7)) << 3) | (off & 7);
    *(uint2*)(dst + osw) = o;
}

// ---------------- common 128x64 GEMM core: BK=64, minimum 2-phase pipeline ----------
// C = A(128 rows,K=1024) x B(64 rows,K=1024)^T, 256 thr = 4 waves (2m x 2n), 64x32/wave.
// LDS 48 KB (2 x (A 16KB + B 8KB)) -> 3 blocks/CU.  Same verified pipeline as rounds 4-8:
// per K-step { issue STAGE(other buf, kt+1); ds_read cur; 16 MFMA; vmcnt(0); ONE barrier }.
// Sources pre-swizzled chunk^=row&7; ds_read_b128 at chunk ((kk*4+quad)^(l4&7)) -> 0 conflicts.
__device__ __forceinline__ void gemm_core_12864(const u16* __restrict__ Ab,
                                                const u16* __restrict__ Bb,
                                                u16* __restrict__ sm,
                                                f32x4 acc[4][2]) {
    const int tid  = threadIdx.x;
    const int wave = tid >> 6, lane = tid & 63;
    const int quad = lane >> 4, l4 = lane & 15, s7 = l4 & 7;
    const int wm = wave >> 1, wn = wave & 1;

    const int srow = tid >> 3, sch = tid & 7;          // staging: 32 rows/call, 8 chunks/row
    const u16* Asrc = Ab + (size_t)srow * D_MODEL + sch * 8;
    const u16* Bsrc = Bb + (size_t)srow * D_MODEL + sch * 8;

    // buffer: base 0 or 12288 u16; A (8192 u16) at base, B (4096 u16) at base+8192
#define STG6(base_, kt_) do {                                                         \
    const size_t ko_ = (size_t)(kt_) * 64;                                            \
    u16* const Ad_ = sm + (base_) + wave * 512;                                       \
    u16* const Bd_ = sm + (base_) + 8192 + wave * 512;                                \
    _Pragma("unroll")                                                                 \
    for (int c_ = 0; c_ < 4; c_++)                                                    \
        gl2lds16(Asrc + (size_t)c_ * 32 * D_MODEL + ko_, Ad_ + c_ * 2048);            \
    _Pragma("unroll")                                                                 \
    for (int c_ = 0; c_ < 2; c_++)                                                    \
        gl2lds16(Bsrc + (size_t)c_ * 32 * D_MODEL + ko_, Bd_ + c_ * 2048);            \
} while (0)

    STG6(0, 0);
    asm volatile("s_waitcnt vmcnt(0)" ::: "memory");
    __builtin_amdgcn_s_barrier();

    for (int kt = 0; kt < 16; ++kt) {
        const int cur = (kt & 1) ? 12288 : 0;
        if (kt < 15) {                                   // issue next tile into other buffer
            if (kt & 1) STG6(0, kt + 1); else STG6(12288, kt + 1);
        }
        const u16* Ar = sm + cur;
        const u16* Br = sm + cur + 8192;
        bf16x8 af[4][2], bfr[2][2];
#pragma unroll
        for (int mt = 0; mt < 4; mt++) {
            const int row = wm * 64 + mt * 16 + l4;
#pragma unroll
            for (int kk = 0; kk < 2; kk++)
                af[mt][kk] = *(const bf16x8*)&Ar[row * 64 + (((kk << 2) + quad) ^ s7) * 8];
        }
#pragma unroll
        for (int nt = 0; nt < 2; nt++) {
            const int row = wn * 32 + nt * 16 + l4;
#pragma unroll
            for (int kk = 0; kk < 2; kk++)
                bfr[nt][kk] = *(const bf16x8*)&Br[row * 64 + (((kk << 2) + quad) ^ s7) * 8];
        }
        __builtin_amdgcn_s_setprio(1);
#pragma unroll
        for (int kk = 0; kk < 2; kk++)
#pragma unroll
            for (int mt = 0; mt < 4; mt++)
#pragma unroll
                for (int nt = 0; nt < 2; nt++)
                    acc[mt][nt] = __builtin_amdgcn_mfma_f32_16x16x32_bf16(af[mt][kk], bfr[nt][kk], acc[mt][nt], 0, 0, 0);
        __builtin_amdgcn_s_setprio(0);
        asm volatile("s_waitcnt vmcnt(0)" ::: "memory"); // next tile fully landed (mine)
        __builtin_amdgcn_s_barrier();                    // ... and everyone's; reads done too
    }
#undef STG6
}

// ---------------- Fused QKV projection GEMM ----------------
// Flat grid 1536 (= 2 exact waves at 3 blocks/CU).
// bid<512: Q (32m x 16n); 512..1023: K; 1024..1535: V^T (8m x 64n, C = Wv x^T).
// Kb: kappa folded into ROW order (prow) + chunk^=prow&7.  Vt: natural + chunk^=feat&7.
__global__ __launch_bounds__(256, 3) void gemm_qkv(const u16* __restrict__ xb,
                                                   const u16* __restrict__ wq,
                                                   const u16* __restrict__ wk,
                                                   const u16* __restrict__ wv,
                                                   u16* __restrict__ Qb, u16* __restrict__ Kb,
                                                   u16* __restrict__ Vt) {
    __shared__ __align__(16) u16 sm[24576];              // 48 KB
    const int bid = blockIdx.x;
    const u16 *Ab, *Bb;
    int m0, n0, sel;
    if (bid < 1024) {
        sel = bid >> 9;                                  // 0=Q, 1=K
        const int t = bid & 511;
        m0 = (t >> 4) * 128; n0 = (t & 15) * 64;
        Ab = xb + (size_t)m0 * D_MODEL;
        Bb = (sel ? wk : wq) + (size_t)n0 * D_MODEL;
    } else {
        sel = 2;
        const int t = bid - 1024;
        m0 = (t >> 6) * 128; n0 = (t & 63) * 64;         // m = features, n = tokens
        Ab = wv + (size_t)m0 * D_MODEL;
        Bb = xb + (size_t)n0 * D_MODEL;
    }

    f32x4 acc[4][2] = {};
    gemm_core_12864(Ab, Bb, sm, acc);

    const int lane = threadIdx.x & 63, quad = lane >> 4, l4 = lane & 15;
    const int wave = threadIdx.x >> 6, wm = wave >> 1, wn = wave & 1;
#pragma unroll
    for (int mt = 0; mt < 4; mt++)
#pragma unroll
        for (int nt = 0; nt < 2; nt++)
#pragma unroll
            for (int r = 0; r < 4; r++) {
                const int mrow = wm * 64 + mt * 16 + quad * 4 + r;
                const int ncol = wn * 32 + nt * 16 + l4;
                const float v = acc[mt][nt][r];
                if (sel == 0) {
                    Qb[(size_t)(m0 + mrow) * D_MODEL + n0 + ncol] = f32_to_bf16(v * C2);
                } else if (sel == 1) {
                    // kappa row-permutation within 32-token group + chunk^=prow&7
                    const int k5 = mrow & 31;
                    const int prow = (mrow & 96) | (((k5 >> 2) & 1) << 4) |
                                     (((k5 >> 3) & 3) << 2) | (k5 & 3);
                    const int ch = wn * 4 + nt * 2 + (l4 >> 3);    // chunk within 64-col head slice
                    const int csw = (((ch ^ (prow & 7)) << 3)) | (l4 & 7);
                    Kb[(size_t)(m0 + prow) * D_MODEL + n0 + csw] = f32_to_bf16(v);
                } else {
                    // natural token order, chunk^=feature&7 within 64-token window
                    const int ch = wn * 4 + nt * 2 + (l4 >> 3);
                    const int csw = (((ch ^ (mrow & 7)) << 3)) | (l4 & 7);
                    Vt[(size_t)(m0 + mrow) * NTOKENS + n0 + csw] = f32_to_bf16(v);
                }
            }
}

// ---------------- Output projection GEMM: fp32 out, 512 blocks (full machine) ----------------
// A = attn output O (pre-swizzled store in attn), B = wo (pre-swizzled by cvt_all).
__global__ __launch_bounds__(256, 3) void gemm_out(const u16* __restrict__ A,
                                                   const u16* __restrict__ Bw,
                                                   float* __restrict__ C) {
    __shared__ __align__(16) u16 sm[24576];              // 48 KB
    const int bid = blockIdx.x;
    const int m0 = (bid >> 4) * 128, n0 = (bid & 15) * 64;

    f32x4 acc[4][2] = {};
    gemm_core_12864(A + (size_t)m0 * D_MODEL, Bw + (size_t)n0 * D_MODEL, sm, acc);

    const int lane = threadIdx.x & 63, quad = lane >> 4, l4 = lane & 15;
    const int wave = threadIdx.x >> 6, wm = wave >> 1, wn = wave & 1;
#pragma unroll
    for (int mt = 0; mt < 4; mt++)
#pragma unroll
        for (int nt = 0; nt < 2; nt++)
#pragma unroll
            for (int r = 0; r < 4; r++) {
                const int mrow = wm * 64 + mt * 16 + quad * 4 + r;
                const int ncol = wn * 32 + nt * 16 + l4;
                C[(size_t)(m0 + mrow) * D_MODEL + n0 + ncol] = acc[mt][nt][r];
            }
}

// ---------------- Flash attention v5c: gl2lds staging, no kv-split, 2-phase pipeline ----------
// (unchanged from round 8 — verified; kappa lives in Kb's row order, chunk^=row&7 swizzle)
__global__ __launch_bounds__(256, 4) void attn(const u16* __restrict__ Q,
                                               const u16* __restrict__ K,
                                               const u16* __restrict__ Vt,
                                               u16* __restrict__ O) {
    __shared__ __align__(16) u16 smem[16384];          // 32 KB: K 2x4096 + V 2x4096 u16
    u16* KsB = smem;
    u16* VsB = smem + 8192;

    const int tid  = threadIdx.x;
    const int wave = tid >> 6, lane = tid & 63;
    const int quad = lane >> 4, l4 = lane & 15;
    const int qg = wave;
    const int bid = blockIdx.x;
    const int h  = (bid & 7) | (((bid >> 3) & 1) << 3);
    const int b  = (bid >> 4) & 1;
    const int q0 = (bid >> 5) * 128;
    const size_t headoff = (size_t)b * SEQ * D_MODEL + (size_t)h * D_K;

    // staging sources (per-lane): wave w stages K token-rows [w*16,w*16+16) and
    // V feature-rows [w*16,w*16+16), 16B per lane, two calls of 8 rows each.
    const int srow8 = lane >> 3, sch = lane & 7;
    const u16* srcK = K  + headoff + (size_t)(wave * 16 + srow8) * D_MODEL + sch * 8;
    const u16* srcV = Vt + (size_t)(h * 64 + wave * 16 + srow8) * NTOKENS + (size_t)b * SEQ + sch * 8;
    u16* const dK0 = KsB + (wave * 16) * 64;
    u16* const dK1 = KsB + (wave * 16 + 8) * 64;
    u16* const dV0 = VsB + (wave * 16) * 64;
    u16* const dV1 = VsB + (wave * 16 + 8) * 64;

#define ASTG(buf_, t_) do {                                                  \
    const size_t kt_ = (size_t)(t_) * 64 * D_MODEL;                          \
    const size_t vt_ = (size_t)(t_) * 64;                                    \
    gl2lds16(srcK + kt_,                       dK0 + (buf_));                \
    gl2lds16(srcK + kt_ + 8 * D_MODEL,         dK1 + (buf_));                \
    gl2lds16(srcV + vt_,                       dV0 + (buf_));                \
    gl2lds16(srcV + vt_ + (size_t)8 * NTOKENS, dV1 + (buf_));                \
} while (0)

    // Q fragments straight from global (one-time): 2 q-subtiles x 2 k-halves
    bf16x8 qa[2][2];
#pragma unroll
    for (int qs = 0; qs < 2; qs++) {
        const u16* qp = Q + headoff + (size_t)(q0 + qg * 32 + qs * 16 + l4) * D_MODEL + quad * 8;
        qa[qs][0] = *(const bf16x8*)qp;
        qa[qs][1] = *(const bf16x8*)(qp + 32);
    }

    // all-ones bf16 B-fragment for denominator MFMA
    union { u32 u[4]; bf16x8 v; } onesu;
#pragma unroll
    for (int i = 0; i < 4; i++) onesu.u[i] = 0x3F803F80u;

    f32x4 acc_o[2][4] = {};
    f32x4 acc_l[2] = {};
    const int sw7 = l4 & 7;

    ASTG(0, 0);
    asm volatile("s_waitcnt vmcnt(0)" ::: "memory");
    __builtin_amdgcn_s_barrier();

    for (int it = 0; it < 32; ++it) {
        const int cur = (it & 1) ? 4096 : 0;
        if (it < 31) { if (it & 1) ASTG(0, it + 1); else ASTG(4096, it + 1); }
        const u16* ksr = KsB + cur;
        const u16* vsr = VsB + cur;

        // S^T = K Q^T for 64 keys (2 kf halves x 2 n2p tiles) x 32 q; exp2 -> pp per kf
        union { u32 u[4]; bf16x8 v; } pp[2][2];
#pragma unroll
        for (int kf = 0; kf < 2; kf++) {
            bf16x8 kb[2][2];
#pragma unroll
            for (int n2p = 0; n2p < 2; n2p++) {
                const int krow = kf * 32 + n2p * 16 + l4;
                kb[n2p][0] = *(const bf16x8*)&ksr[krow * 64 + ((quad       ^ sw7) * 8)];
                kb[n2p][1] = *(const bf16x8*)&ksr[krow * 64 + (((4 + quad) ^ sw7) * 8)];
            }
            f32x4 sacc[2][2] = {};
            __builtin_amdgcn_s_setprio(1);
#pragma unroll
            for (int qs = 0; qs < 2; qs++)
#pragma unroll
                for (int n2p = 0; n2p < 2; n2p++) {
                    sacc[qs][n2p] = __builtin_amdgcn_mfma_f32_16x16x32_bf16(kb[n2p][0], qa[qs][0], sacc[qs][n2p], 0, 0, 0);
                    sacc[qs][n2p] = __builtin_amdgcn_mfma_f32_16x16x32_bf16(kb[n2p][1], qa[qs][1], sacc[qs][n2p], 0, 0, 0);
                }
            __builtin_amdgcn_s_setprio(0);
#pragma unroll
            for (int qs = 0; qs < 2; qs++)
#pragma unroll
                for (int n2p = 0; n2p < 2; n2p++) {
                    float p0 = __builtin_amdgcn_exp2f(sacc[qs][n2p][0]);
                    float p1 = __builtin_amdgcn_exp2f(sacc[qs][n2p][1]);
                    float p2 = __builtin_amdgcn_exp2f(sacc[qs][n2p][2]);
                    float p3 = __builtin_amdgcn_exp2f(sacc[qs][n2p][3]);
                    pp[qs][kf].u[n2p * 2]     = cvt_pk_bf16(p0, p1);
                    pp[qs][kf].u[n2p * 2 + 1] = cvt_pk_bf16(p2, p3);
                }
        }

        // O += P V over both key-halves; denominator via constant-ones B fragment
        __builtin_amdgcn_s_setprio(1);
#pragma unroll
        for (int dvt = 0; dvt < 4; dvt++) {
            const int vrow = dvt * 16 + l4;
#pragma unroll
            for (int kf = 0; kf < 2; kf++) {
                bf16x8 vfr = *(const bf16x8*)&vsr[vrow * 64 + ((((kf << 2) + quad) ^ sw7) * 8)];
#pragma unroll
                for (int qs = 0; qs < 2; qs++)
                    acc_o[qs][dvt] = __builtin_amdgcn_mfma_f32_16x16x32_bf16(pp[qs][kf].v, vfr, acc_o[qs][dvt], 0, 0, 0);
            }
        }
#pragma unroll
        for (int qs = 0; qs < 2; qs++)
#pragma unroll
            for (int kf = 0; kf < 2; kf++)
                acc_l[qs] = __builtin_amdgcn_mfma_f32_16x16x32_bf16(pp[qs][kf].v, onesu.v, acc_l[qs], 0, 0, 0);
        __builtin_amdgcn_s_setprio(0);

        asm volatile("s_waitcnt vmcnt(0)" ::: "memory");
        __builtin_amdgcn_s_barrier();
    }

    // epilogue: acc_l is the FULL row sum (each wave saw all keys) -> direct store
#pragma unroll
    for (int qs = 0; qs < 2; qs++)
#pragma unroll
        for (int r = 0; r < 4; r++) {
            const float linv = 1.f / acc_l[qs][r];
            const int qrow = q0 + qg * 32 + qs * 16 + quad * 4 + r;
#pragma unroll
            for (int dvt = 0; dvt < 4; dvt++) {
                // GEMM chunk swizzle: chunk ^= qrow&7 within the head's 64-col slice
                const int csw = (((dvt * 2 + (l4 >> 3)) ^ (qrow & 7)) << 3) | (l4 & 7);
                O[headoff + (size_t)qrow * D_MODEL + csw] = f32_to_bf16(acc_o[qs][dvt][r] * linv);
            }
        }
#undef ASTG
}

// ---------------- launch ----------------
extern "C" void kernel_launch(void* const* d_in, const int* in_sizes, int n_in,
                              void* d_out, int out_size, void* d_ws, size_t ws_size,
                              hipStream_t stream) {
    const float* x  = (const float*)d_in[0];
    const float* Wq = (const float*)d_in[1];
    const float* Wk = (const float*)d_in[2];
    const float* Wv = (const float*)d_in[3];
    const float* Wo = (const float*)d_in[4];

    const int NW = D_MODEL * D_MODEL;      // 1,048,576

    char* ws = (char*)d_ws;
    u16* xb = (u16*)ws;                    // 8 MB; reused as attn output O
    u16* wq = (u16*)(ws + (8u << 20));
    u16* wk = wq + NW;
    u16* wv = wk + NW;
    u16* wo = wv + NW;
    u16* Qb  = (u16*)(ws + (16u << 20));
    u16* Kb  = (u16*)(ws + (24u << 20));   // kappa-row-permuted + chunk-swizzled
    u16* Vtb = (u16*)(ws + (32u << 20));   // V^T natural order + chunk-swizzled

    cvt_all<<<8192, 256, 0, stream>>>(x, Wq, Wk, Wv, Wo, xb, wq, wk, wv, wo);

    gemm_qkv<<<1536, 256, 0, stream>>>(xb, wq, wk, wv, Qb, Kb, Vtb);

    attn<<<512, 256, 0, stream>>>(Qb, Kb, Vtb, xb);

    gemm_out<<<512, 256, 0, stream>>>(xb, wo, (float*)d_out);
}